// Round 1
// baseline (551.737 us; speedup 1.0000x reference)
//
#include <hip/hip_runtime.h>

#define B_ROWS 1024
#define D_DIM  512
#define C_CLS  100000
#define C_PAD  100096   // 782 * 128
#define N_TILES 782
#define M_TILES 8

typedef unsigned short u16;
typedef __attribute__((ext_vector_type(8))) short bf16x8;
typedef __attribute__((ext_vector_type(4))) float f32x4;

__device__ __forceinline__ u16 f2bf(float f) {
  unsigned u = __float_as_uint(f);
  u += 0x7fffu + ((u >> 16) & 1u);   // round-to-nearest-even
  return (u16)(u >> 16);
}

__device__ __forceinline__ void gll16(const void* g, void* l) {
  __builtin_amdgcn_global_load_lds(
      (const __attribute__((address_space(1))) unsigned int*)g,
      (__attribute__((address_space(3))) unsigned int*)l, 16, 0, 0);
}

// One wave per row: L2-normalize a 512-float row, emit bf16. Rows >= nvalid
// (weight pad rows) emit zeros (they also get masked in the GEMM epilogue).
__global__ void norm_rows_kernel(const float* __restrict__ in,
                                 u16* __restrict__ out, int nvalid)
{
  const int row  = blockIdx.x * 4 + (threadIdx.x >> 6);
  const int lane = threadIdx.x & 63;
  float4 v0 = make_float4(0.f, 0.f, 0.f, 0.f);
  float4 v1 = make_float4(0.f, 0.f, 0.f, 0.f);
  if (row < nvalid) {
    const float4* r = (const float4*)(in + (size_t)row * D_DIM);
    v0 = r[lane];
    v1 = r[lane + 64];
  }
  float ss = v0.x*v0.x + v0.y*v0.y + v0.z*v0.z + v0.w*v0.w
           + v1.x*v1.x + v1.y*v1.y + v1.z*v1.z + v1.w*v1.w;
#pragma unroll
  for (int m = 1; m < 64; m <<= 1) ss += __shfl_xor(ss, m);
  const float inv = 1.0f / fmaxf(sqrtf(ss), 1e-12f);  // rows>=nvalid: 0*big=0
  ushort4 o0, o1;
  o0.x = f2bf(v0.x * inv); o0.y = f2bf(v0.y * inv);
  o0.z = f2bf(v0.z * inv); o0.w = f2bf(v0.w * inv);
  o1.x = f2bf(v1.x * inv); o1.y = f2bf(v1.y * inv);
  o1.z = f2bf(v1.z * inv); o1.w = f2bf(v1.w * inv);
  ushort4* orow = (ushort4*)(out + (size_t)row * D_DIM);
  orow[lane]      = o0;
  orow[lane + 64] = o1;
}

// 128x128 tile bf16 MFMA GEMM (Bt form: both operands row-major, K contiguous)
// fused with ArcFace margin + exp + per-row partial sum-of-exp.
__global__ __launch_bounds__(256, 3) void arc_gemm(
    const u16* __restrict__ fn, const u16* __restrict__ wn,
    const int* __restrict__ targets, float* __restrict__ psum,
    float* __restrict__ tlogit)
{
  __shared__ u16 As[128 * 32];
  __shared__ u16 Ws[128 * 32];
  __shared__ int tg[128];

  const int tid = threadIdx.x;
  const int bx = blockIdx.x;
  const int tile_m = (bx & 7) << 7;   // consecutive blocks share tile_n -> W L2-hot
  const int tile_n = (bx >> 3) << 7;

  if (tid < 128) tg[tid] = targets[tile_m + tid];

  const int wave = tid >> 6, lane = tid & 63;
  const int wm = wave >> 1, wno = wave & 1;
  const int quad = lane >> 4, l15 = lane & 15;

  f32x4 acc[4][4] = {};

  // staging: thread t loads 8 contiguous bf16 (16B); LDS dest = linear tid*16B
  // (wave-uniform base + lane*16 — required by global_load_lds)
  const u16* Ag = fn + (size_t)(tile_m + (tid >> 2)) * D_DIM + (tid & 3) * 8;
  const u16* Wg = wn + (size_t)(tile_n + (tid >> 2)) * D_DIM + (tid & 3) * 8;
  u16* Asd0 = As + tid * 8;
  u16* Asd1 = As + 2048 + tid * 8;
  u16* Wsd0 = Ws + tid * 8;
  u16* Wsd1 = Ws + 2048 + tid * 8;

  const u16* ApA = As + (wm * 64 + l15) * 32 + quad * 8;
  const u16* ApW = Ws + (wno * 64 + l15) * 32 + quad * 8;

  for (int k0 = 0; k0 < D_DIM; k0 += 32) {
    gll16(Ag + k0, Asd0);
    gll16(Ag + 64 * D_DIM + k0, Asd1);
    gll16(Wg + k0, Wsd0);
    gll16(Wg + 64 * D_DIM + k0, Wsd1);
    __syncthreads();   // compiler drains vmcnt before s_barrier
    bf16x8 af[4], wf[4];
#pragma unroll
    for (int r = 0; r < 4; r++) af[r] = *(const bf16x8*)(ApA + r * 16 * 32);
#pragma unroll
    for (int r = 0; r < 4; r++) wf[r] = *(const bf16x8*)(ApW + r * 16 * 32);
#pragma unroll
    for (int rm = 0; rm < 4; rm++)
#pragma unroll
      for (int rn = 0; rn < 4; rn++)
        acc[rm][rn] = __builtin_amdgcn_mfma_f32_16x16x32_bf16(
            af[rm], wf[rn], acc[rm][rn], 0, 0, 0);
    __syncthreads();
  }

  // Epilogue: logits = 30*cos (target col: 30*phi); accumulate exp(l-30).
  const float Sc   = 30.0f;
  const float COSM = 0.9553364891256060f;
  const float SINM = 0.2955202066613396f;
  const float THc  = -0.9553364891256060f;
  const float MMc  = 0.0886560619984019f;

#pragma unroll
  for (int rm = 0; rm < 4; rm++) {
#pragma unroll
    for (int reg = 0; reg < 4; reg++) {
      const int bl = wm * 64 + rm * 16 + quad * 4 + reg;  // C/D row = M index
      const int b = tile_m + bl;
      const int tgt = tg[bl];
      float s = 0.0f;
#pragma unroll
      for (int rn = 0; rn < 4; rn++) {
        const int c = tile_n + wno * 64 + rn * 16 + l15;  // C/D col = N index
        const float cosv = acc[rm][rn][reg];
        float logit = Sc * cosv;
        if (c == tgt) {
          const float sine = sqrtf(fmaxf(1.0f - cosv * cosv, 0.0f));
          float phi = cosv * COSM - sine * SINM;
          phi = (cosv > THc) ? phi : (cosv - MMc);
          logit = Sc * phi;
          tlogit[b] = logit;   // exactly one lane in the grid owns (b, tgt)
        }
        s += (c < C_CLS) ? __expf(logit - 30.0f) : 0.0f;  // mask pad columns
      }
      // reduce across the 16 lanes holding this row's 16 columns
      s += __shfl_xor(s, 1);
      s += __shfl_xor(s, 2);
      s += __shfl_xor(s, 4);
      s += __shfl_xor(s, 8);
      if (l15 == 0) atomicAdd(psum + b, s);
    }
  }
}

__global__ void finalize_loss(const float* __restrict__ psum,
                              const float* __restrict__ tlogit,
                              float* __restrict__ out)
{
  const int tid = threadIdx.x;
  float s = 0.0f;
  for (int i = tid; i < B_ROWS; i += 256)
    s += 30.0f + logf(psum[i]) - tlogit[i];   // logsumexp - target logit
#pragma unroll
  for (int m = 1; m < 64; m <<= 1) s += __shfl_xor(s, m);
  __shared__ float red[4];
  if ((tid & 63) == 0) red[tid >> 6] = s;
  __syncthreads();
  if (tid == 0) out[0] = (red[0] + red[1] + red[2] + red[3]) * (1.0f / B_ROWS);
}

extern "C" void kernel_launch(void* const* d_in, const int* in_sizes, int n_in,
                              void* d_out, int out_size, void* d_ws, size_t ws_size,
                              hipStream_t stream) {
  const float* feat = (const float*)d_in[0];
  const float* wt   = (const float*)d_in[1];
  const int*   tgt  = (const int*)d_in[2];
  float* out = (float*)d_out;
  char* ws = (char*)d_ws;

  // ws layout: fn 1 MB | wn 102,498,304 B | psum 4 KB | tlogit 4 KB  (~103.6 MB)
  u16* fn = (u16*)ws;
  u16* wn = (u16*)(ws + (size_t)B_ROWS * D_DIM * 2);
  float* psum = (float*)(ws + (size_t)B_ROWS * D_DIM * 2 + (size_t)C_PAD * D_DIM * 2);
  float* tlogit = psum + B_ROWS;

  hipMemsetAsync(psum, 0, B_ROWS * sizeof(float), stream);
  norm_rows_kernel<<<B_ROWS / 4, 256, 0, stream>>>(feat, fn, B_ROWS);
  norm_rows_kernel<<<C_PAD / 4, 256, 0, stream>>>(wt, wn, C_CLS);
  arc_gemm<<<N_TILES * M_TILES, 256, 0, stream>>>(fn, wn, tgt, psum, tlogit);
  finalize_loss<<<1, 256, 0, stream>>>(psum, tlogit, out);
}

// Round 2
// 460.450 us; speedup vs baseline: 1.1983x; 1.1983x over previous
//
#include <hip/hip_runtime.h>

#define B_ROWS 1024
#define D_DIM  512
#define C_CLS  100000
#define N_TILES 782     // ceil(100000/128)
#define GRID_NJ 98      // 98*8 = 784 >= 782 (XCD-swizzle padding, 16 idle blocks)

typedef unsigned short u16;
typedef __attribute__((ext_vector_type(8))) short bf16x8;
typedef __attribute__((ext_vector_type(4))) float f32x4;

__device__ __forceinline__ u16 f2bf(float f) {
  unsigned u = __float_as_uint(f);
  u += 0x7fffu + ((u >> 16) & 1u);   // round-to-nearest-even
  return (u16)(u >> 16);
}

// pack 8 fp32 -> 8 bf16 (RTZ: take high 16 bits) via v_perm_b32
__device__ __forceinline__ bf16x8 pack8(float4 a, float4 b) {
  union { bf16x8 v; unsigned u[4]; } r;
  r.u[0] = __builtin_amdgcn_perm(__float_as_uint(a.y), __float_as_uint(a.x), 0x07060302u);
  r.u[1] = __builtin_amdgcn_perm(__float_as_uint(a.w), __float_as_uint(a.z), 0x07060302u);
  r.u[2] = __builtin_amdgcn_perm(__float_as_uint(b.y), __float_as_uint(b.x), 0x07060302u);
  r.u[3] = __builtin_amdgcn_perm(__float_as_uint(b.w), __float_as_uint(b.z), 0x07060302u);
  return r.v;
}

__device__ __forceinline__ void gll16(const void* g, void* l) {
  __builtin_amdgcn_global_load_lds(
      (const __attribute__((address_space(1))) unsigned int*)g,
      (__attribute__((address_space(3))) unsigned int*)l, 16, 0, 0);
}

// One wave per row: L2-normalize a 512-float row, emit bf16 (features only).
__global__ void norm_feat_kernel(const float* __restrict__ in, u16* __restrict__ out)
{
  const int row  = blockIdx.x * 4 + (threadIdx.x >> 6);
  const int lane = threadIdx.x & 63;
  const float4* r = (const float4*)(in + (size_t)row * D_DIM);
  float4 v0 = r[lane];
  float4 v1 = r[lane + 64];
  float ss = v0.x*v0.x + v0.y*v0.y + v0.z*v0.z + v0.w*v0.w
           + v1.x*v1.x + v1.y*v1.y + v1.z*v1.z + v1.w*v1.w;
#pragma unroll
  for (int m = 1; m < 64; m <<= 1) ss += __shfl_xor(ss, m);
  const float inv = 1.0f / fmaxf(sqrtf(ss), 1e-12f);
  ushort4 o0, o1;
  o0.x = f2bf(v0.x * inv); o0.y = f2bf(v0.y * inv);
  o0.z = f2bf(v0.z * inv); o0.w = f2bf(v0.w * inv);
  o1.x = f2bf(v1.x * inv); o1.y = f2bf(v1.y * inv);
  o1.z = f2bf(v1.z * inv); o1.w = f2bf(v1.w * inv);
  ushort4* orow = (ushort4*)(out + (size_t)row * D_DIM);
  orow[lane]      = o0;
  orow[lane + 64] = o1;
}

// 128x128 bf16 MFMA GEMM. A = pre-normalized bf16 features (global_load_lds).
// W = RAW fp32 weights: loaded, packed to bf16 in-register, ds_write to LDS;
// per-row sum-of-squares accumulated across K, 1/||w|| applied in the epilogue
// (cosine is scale-invariant). Fused ArcFace margin + exp + row partial sums.
__global__ __launch_bounds__(256, 4) void arc_gemm(
    const u16* __restrict__ fn, const float* __restrict__ wt,
    const int* __restrict__ targets, float* __restrict__ psum,
    float* __restrict__ tlogit)
{
  __shared__ u16 As[128 * 32];
  __shared__ u16 Ws[128 * 32];
  __shared__ int tg[128];
  __shared__ float winv[128];

  const int tid = threadIdx.x;
  const int bx  = blockIdx.x;
  // XCD-aware: bx%8 = XCD (round-robin dispatch); 8 consecutive blocks on one
  // XCD share tile_n -> W tile fetched beyond-L2 once, reused 8x from L2.
  const int xcd = bx & 7;
  const int l   = bx >> 3;
  const int tile_ni = (l >> 3) * 8 + xcd;
  if (tile_ni >= N_TILES) return;
  const int tile_m = (l & 7) << 7;
  const int tile_n = tile_ni << 7;

  if (tid < 128) tg[tid] = targets[tile_m + tid];

  const int wave = tid >> 6, lane = tid & 63;
  const int wm = wave >> 1, wno = wave & 1;
  const int quad = lane >> 4, l15 = lane & 15;

  f32x4 acc[4][4] = {};

  // Staging thread t owns rows (t>>2, t>>2+64) and XOR-swizzled k-chunk:
  // LDS slot (row, s) holds global chunk s ^ ((row>>1)&3) -> 2-way bank
  // conflicts on ds_read_b128 instead of 8-way; gll16 dest stays linear.
  const int srow   = tid >> 2;
  const int schunk = (tid & 3) ^ ((tid >> 3) & 3);
  const u16* Ag = fn + (size_t)(tile_m + srow) * D_DIM + schunk * 8;
  u16* Asd0 = As + tid * 8;
  u16* Asd1 = As + 2048 + tid * 8;
  const int wr0 = tile_n + srow;
  const int wr1 = wr0 + 64;
  // clamp pad rows (tile 781 extends past 100000); masked in epilogue anyway
  const float* Wg0 = wt + (size_t)min(wr0, C_CLS - 1) * D_DIM + schunk * 8;
  const float* Wg1 = wt + (size_t)min(wr1, C_CLS - 1) * D_DIM + schunk * 8;
  u16* Wsd0 = Ws + tid * 8;
  u16* Wsd1 = Ws + 2048 + tid * 8;

  // read-side swizzle: (row>>1)&3 == (l15>>1)&3 (r*16, wm*64 are 0 mod 8)
  const int rsw = (quad ^ ((l15 >> 1) & 3)) * 8;
  const u16* ApA = As + (wm * 64 + l15) * 32 + rsw;
  const u16* ApW = Ws + (wno * 64 + l15) * 32 + rsw;

  float ssq0 = 0.0f, ssq1 = 0.0f;

  for (int k0 = 0; k0 < D_DIM; k0 += 32) {
    const float4 wa = *(const float4*)(Wg0 + k0);
    const float4 wb = *(const float4*)(Wg0 + k0 + 4);
    const float4 wc = *(const float4*)(Wg1 + k0);
    const float4 wd = *(const float4*)(Wg1 + k0 + 4);
    gll16(Ag + k0, Asd0);
    gll16(Ag + 64 * D_DIM + k0, Asd1);
    ssq0 += wa.x*wa.x + wa.y*wa.y + wa.z*wa.z + wa.w*wa.w
          + wb.x*wb.x + wb.y*wb.y + wb.z*wb.z + wb.w*wb.w;
    ssq1 += wc.x*wc.x + wc.y*wc.y + wc.z*wc.z + wc.w*wc.w
          + wd.x*wd.x + wd.y*wd.y + wd.z*wd.z + wd.w*wd.w;
    *(bf16x8*)Wsd0 = pack8(wa, wb);
    *(bf16x8*)Wsd1 = pack8(wc, wd);
    __syncthreads();
    bf16x8 af[4], wf[4];
#pragma unroll
    for (int r = 0; r < 4; r++) af[r] = *(const bf16x8*)(ApA + r * 16 * 32);
#pragma unroll
    for (int r = 0; r < 4; r++) wf[r] = *(const bf16x8*)(ApW + r * 16 * 32);
#pragma unroll
    for (int rm = 0; rm < 4; rm++)
#pragma unroll
      for (int rn = 0; rn < 4; rn++)
        acc[rm][rn] = __builtin_amdgcn_mfma_f32_16x16x32_bf16(
            af[rm], wf[rn], acc[rm][rn], 0, 0, 0);
    __syncthreads();
  }

  // per-row 1/||w||: reduce ssq over the 4 chunk-threads (consecutive lanes)
  ssq0 += __shfl_xor(ssq0, 1); ssq0 += __shfl_xor(ssq0, 2);
  ssq1 += __shfl_xor(ssq1, 1); ssq1 += __shfl_xor(ssq1, 2);
  if ((tid & 3) == 0) {
    winv[srow]      = 1.0f / fmaxf(sqrtf(ssq0), 1e-12f);
    winv[srow + 64] = 1.0f / fmaxf(sqrtf(ssq1), 1e-12f);
  }
  __syncthreads();

  float wiv[4];
#pragma unroll
  for (int rn = 0; rn < 4; rn++) wiv[rn] = winv[wno * 64 + rn * 16 + l15];

  const float Sc   = 30.0f;
  const float COSM = 0.9553364891256060f;
  const float SINM = 0.2955202066613396f;
  const float THc  = -0.9553364891256060f;
  const float MMc  = 0.0886560619984019f;

#pragma unroll
  for (int rm = 0; rm < 4; rm++) {
#pragma unroll
    for (int reg = 0; reg < 4; reg++) {
      const int bl = wm * 64 + rm * 16 + quad * 4 + reg;  // C/D row = M index
      const int b = tile_m + bl;
      const int tgt = tg[bl];
      float s = 0.0f;
#pragma unroll
      for (int rn = 0; rn < 4; rn++) {
        const int c = tile_n + wno * 64 + rn * 16 + l15;  // C/D col = N index
        const float cosv = acc[rm][rn][reg] * wiv[rn];
        float logit = Sc * cosv;
        if (c == tgt) {
          const float sine = sqrtf(fmaxf(1.0f - cosv * cosv, 0.0f));
          float phi = cosv * COSM - sine * SINM;
          phi = (cosv > THc) ? phi : (cosv - MMc);
          logit = Sc * phi;
          tlogit[b] = logit;   // exactly one lane in the grid owns (b, tgt)
        }
        s += (c < C_CLS) ? __expf(logit - 30.0f) : 0.0f;  // mask pad columns
      }
      s += __shfl_xor(s, 1);
      s += __shfl_xor(s, 2);
      s += __shfl_xor(s, 4);
      s += __shfl_xor(s, 8);
      if (l15 == 0) atomicAdd(psum + b, s);
    }
  }
}

__global__ void finalize_loss(const float* __restrict__ psum,
                              const float* __restrict__ tlogit,
                              float* __restrict__ out)
{
  const int tid = threadIdx.x;
  float s = 0.0f;
  for (int i = tid; i < B_ROWS; i += 256)
    s += 30.0f + logf(psum[i]) - tlogit[i];   // logsumexp - target logit
#pragma unroll
  for (int m = 1; m < 64; m <<= 1) s += __shfl_xor(s, m);
  __shared__ float red[4];
  if ((tid & 63) == 0) red[tid >> 6] = s;
  __syncthreads();
  if (tid == 0) out[0] = (red[0] + red[1] + red[2] + red[3]) * (1.0f / B_ROWS);
}

extern "C" void kernel_launch(void* const* d_in, const int* in_sizes, int n_in,
                              void* d_out, int out_size, void* d_ws, size_t ws_size,
                              hipStream_t stream) {
  const float* feat = (const float*)d_in[0];
  const float* wt   = (const float*)d_in[1];
  const int*   tgt  = (const int*)d_in[2];
  float* out = (float*)d_out;
  char* ws = (char*)d_ws;

  // ws layout: fn 1 MB | psum 4 KB | tlogit 4 KB
  u16* fn = (u16*)ws;
  float* psum = (float*)(ws + (size_t)B_ROWS * D_DIM * 2);
  float* tlogit = psum + B_ROWS;

  hipMemsetAsync(psum, 0, B_ROWS * sizeof(float), stream);
  norm_feat_kernel<<<B_ROWS / 4, 256, 0, stream>>>(feat, fn);
  arc_gemm<<<GRID_NJ * 8 * 8, 256, 0, stream>>>(fn, wt, tgt, psum, tlogit);
  finalize_loss<<<1, 256, 0, stream>>>(psum, tlogit, out);
}